// Round 6
// baseline (1122.605 us; speedup 1.0000x reference)
//
#include <hip/hip_runtime.h>

#define BB  1024
#define TT  512
#define HH  64
#define NBB 16          // batches per block (MFMA N=16); grid = 64 blocks

typedef __attribute__((ext_vector_type(8))) short  short8;   // 8 bf16 (4 VGPR) = MFMA A/B frag
typedef __attribute__((ext_vector_type(4))) short  short4v;  // 8 B
typedef __attribute__((ext_vector_type(4))) float  f32x4;    // MFMA C/D frag

__device__ __forceinline__ unsigned short f2bf(float f) {
    unsigned u = __float_as_uint(f);
    u += 0x7FFF + ((u >> 16) & 1);          // round-to-nearest-even
    return (unsigned short)(u >> 16);
}
__device__ __forceinline__ float bf2f(unsigned short s) {
    return __uint_as_float(((unsigned)s) << 16);
}
__device__ __forceinline__ float sigm(float v) { return 1.0f / (1.0f + __expf(-v)); }
__device__ __forceinline__ float tanh_(float v) { return fmaf(2.0f, sigm(2.0f * v), -1.0f); }

// Split-bf16 MFMA fused 2-layer LSTM, v2.
//  - 4 waves (1/SIMD, waves_per_eu(1,1) -> 512-reg budget/wave). Wave G owns
//    gate tiles {G,G+4,G+8,G+12} of BOTH layers: all persistent state is
//    MFMA-operand-shaped (A-frags + C-accs -> AGPR-native, no shuffle churn).
//  - gates = Wh.hh + Wh.hl + Wl.hh (Wl.hl dropped, ~2^-18 rel) — same 3-term
//    scheme that measured 6.1e-5 absmax in R5.
//  - h stored in EXACT B-fragment order [layer][par][hl][kt][lane][8]: each
//    lane reads its own consecutive 16 B -> conflict-free (R5's stride-36
//    layout caused 8.4M conflict cycles).
//  - Layer 1 one step behind layer 0; parity double-buffer -> 1 barrier/step.
__global__ __launch_bounds__(256)
__attribute__((amdgpu_waves_per_eu(1, 1)))
void lstm_mfma2(const float* __restrict__ x,     // [B,T] (I=1)
                const float* __restrict__ Wih0,  // [256]
                const float* __restrict__ Whh0,  // [256,64]
                const float* __restrict__ bih0,  // [256]
                const float* __restrict__ bhh0,  // [256]
                const float* __restrict__ Wih1,  // [256,64]
                const float* __restrict__ Whh1,  // [256,64]
                const float* __restrict__ bih1,  // [256]
                const float* __restrict__ bhh1,  // [256]
                const float* __restrict__ Wfc,   // [64]
                const float* __restrict__ bfc,   // [1]
                float* __restrict__ out)         // [B]
{
    __shared__ __align__(16) float          s_x[NBB][TT + 1];          // 32.8 KB
    // h fragments, B-operand order: [layer][parity][hi/lo][kt][lane][j]
    __shared__ __align__(16) unsigned short s_hf[2][2][2][2][64][8];   // 4 KB
    __shared__ __align__(16) float          s_h1f[NBB][HH + 4];        // 4.3 KB

    const int tid  = threadIdx.x;
    const int lane = tid & 63;
    const int G    = tid >> 6;    // wave id = unit group (units 16G..16G+15)
    const int q    = lane >> 4;   // quad
    const int n16  = lane & 15;   // batch column
    const int b0   = blockIdx.x * NBB;

    // ---- one-time: A fragments (hi/lo split) + bias/xw ----
    // A-frag (16x16x32): lane holds A[m = n16][k = 8q + j], j = 0..7.
    short8 Ah0[4][2], Al0[4][2];   // layer0: K=64  (Whh0)
    short8 Ah1[4][4], Al1[4][4];   // layer1: K=128 ([Wih1 | Whh1])
    float  bias0[4][4], xw0v[4][4], bias1[4][4];

    for (int gi = 0; gi < 4; ++gi) {
        for (int r = 0; r < 4; ++r) {
            const int row = 64 * gi + 16 * G + 4 * q + r;   // C/D row 4q+r
            bias0[gi][r] = bih0[row] + bhh0[row];
            xw0v[gi][r]  = Wih0[row];
            bias1[gi][r] = bih1[row] + bhh1[row];
        }
        const int rowA = 64 * gi + 16 * G + n16;
        for (int kt = 0; kt < 2; ++kt) {
            const float* src = Whh0 + rowA * 64 + 32 * kt + 8 * q;
            short8 hv, lv;
            for (int j = 0; j < 8; ++j) {
                const float wv = src[j];
                const unsigned short hs = f2bf(wv);
                hv[j] = (short)hs;
                lv[j] = (short)f2bf(wv - bf2f(hs));
            }
            Ah0[gi][kt] = hv; Al0[gi][kt] = lv;
        }
        for (int kt = 0; kt < 4; ++kt) {
            const float* src = (kt < 2) ? (Wih1 + rowA * 64 + 32 * kt + 8 * q)
                                        : (Whh1 + rowA * 64 + 32 * (kt - 2) + 8 * q);
            short8 hv, lv;
            for (int j = 0; j < 8; ++j) {
                const float wv = src[j];
                const unsigned short hs = f2bf(wv);
                hv[j] = (short)hs;
                lv[j] = (short)f2bf(wv - bf2f(hs));
            }
            Ah1[gi][kt] = hv; Al1[gi][kt] = lv;
        }
    }

    // ---- stage x (coalesced) + zero h fragment buffers ----
    for (int i = tid; i < NBB * TT; i += 256) {
        const int nb = i >> 9, pos = i & (TT - 1);
        s_x[nb][pos] = x[(b0 + nb) * TT + pos];
    }
    for (int i = tid; i < (int)(sizeof(s_hf) / 4); i += 256)
        ((unsigned*)s_hf)[i] = 0u;

    float c0[4] = {0, 0, 0, 0};   // cell state, layer0 units 16G+4q..+3, batch n16
    float c1[4] = {0, 0, 0, 0};   // cell state, layer1 same units

    // h-write address components (unit u0 = 16G + 4q, k-index = u)
    const int u0   = 16 * G + 4 * q;
    const int kt_w = u0 >> 5;            // which K-tile
    const int ln_w = (((u0 >> 3) & 3) << 4) + n16;  // target fragment lane
    const int jb   = u0 & 7;             // 0 or 4: j offset within octet

    __syncthreads();

    for (int s = 0; s <= TT; ++s) {
        const int p = (s & 1) ^ 1;   // read parity
        const int w = s & 1;         // write parity

        // ---- B fragments: conflict-free consecutive-16B reads ----
        short8 B0h[2], B0l[2], B1h[2], B1l[2];
#pragma unroll
        for (int kt = 0; kt < 2; ++kt) {
            B0h[kt] = *(const short8*)&s_hf[0][p][0][kt][lane][0];
            B0l[kt] = *(const short8*)&s_hf[0][p][1][kt][lane][0];
            B1h[kt] = *(const short8*)&s_hf[1][p][0][kt][lane][0];
            B1l[kt] = *(const short8*)&s_hf[1][p][1][kt][lane][0];
        }
        const float xv = s_x[n16][(s < TT) ? s : 0];   // s==TT result discarded

        // ---- MFMA: layer0 gates(s), layer1 gates(s-1) ----
        f32x4 acc0[4], acc1[4];
#pragma unroll
        for (int gi = 0; gi < 4; ++gi) {
            f32x4 a0, a1;
#pragma unroll
            for (int r = 0; r < 4; ++r) {
                a0[r] = fmaf(xw0v[gi][r], xv, bias0[gi][r]);
                a1[r] = bias1[gi][r];
            }
#pragma unroll
            for (int kt = 0; kt < 2; ++kt) {
                a0 = __builtin_amdgcn_mfma_f32_16x16x32_bf16(Ah0[gi][kt], B0h[kt], a0, 0, 0, 0);
                a0 = __builtin_amdgcn_mfma_f32_16x16x32_bf16(Ah0[gi][kt], B0l[kt], a0, 0, 0, 0);
                a0 = __builtin_amdgcn_mfma_f32_16x16x32_bf16(Al0[gi][kt], B0h[kt], a0, 0, 0, 0);
            }
#pragma unroll
            for (int kt = 0; kt < 2; ++kt) {
                a1 = __builtin_amdgcn_mfma_f32_16x16x32_bf16(Ah1[gi][kt],     B0h[kt], a1, 0, 0, 0);
                a1 = __builtin_amdgcn_mfma_f32_16x16x32_bf16(Ah1[gi][kt],     B0l[kt], a1, 0, 0, 0);
                a1 = __builtin_amdgcn_mfma_f32_16x16x32_bf16(Al1[gi][kt],     B0h[kt], a1, 0, 0, 0);
                a1 = __builtin_amdgcn_mfma_f32_16x16x32_bf16(Ah1[gi][kt + 2], B1h[kt], a1, 0, 0, 0);
                a1 = __builtin_amdgcn_mfma_f32_16x16x32_bf16(Ah1[gi][kt + 2], B1l[kt], a1, 0, 0, 0);
                a1 = __builtin_amdgcn_mfma_f32_16x16x32_bf16(Al1[gi][kt + 2], B1h[kt], a1, 0, 0, 0);
            }
            acc0[gi] = a0; acc1[gi] = a1;
        }

        // ---- layer0 update, timestep s (skip at s==TT) ----
        if (s < TT) {
            short4v vh, vl;
#pragma unroll
            for (int r = 0; r < 4; ++r) {
                const float i_ = sigm(acc0[0][r]);
                const float f_ = sigm(acc0[1][r]);
                const float g_ = tanh_(acc0[2][r]);
                const float o_ = sigm(acc0[3][r]);
                c0[r] = fmaf(f_, c0[r], i_ * g_);
                const float h = o_ * tanh_(c0[r]);
                const unsigned short hs = f2bf(h);
                vh[r] = (short)hs;
                vl[r] = (short)f2bf(h - bf2f(hs));
            }
            *(short4v*)&s_hf[0][w][0][kt_w][ln_w][jb] = vh;
            *(short4v*)&s_hf[0][w][1][kt_w][ln_w][jb] = vl;
        }
        // ---- layer1 update, timestep s-1 (skip at s==0) ----
        if (s >= 1) {
            short4v vh, vl; f32x4 hf;
#pragma unroll
            for (int r = 0; r < 4; ++r) {
                const float i_ = sigm(acc1[0][r]);
                const float f_ = sigm(acc1[1][r]);
                const float g_ = tanh_(acc1[2][r]);
                const float o_ = sigm(acc1[3][r]);
                c1[r] = fmaf(f_, c1[r], i_ * g_);
                const float h = o_ * tanh_(c1[r]);
                const unsigned short hs = f2bf(h);
                vh[r] = (short)hs;
                vl[r] = (short)f2bf(h - bf2f(hs));
                hf[r] = h;
            }
            *(short4v*)&s_hf[1][w][0][kt_w][ln_w][jb] = vh;
            *(short4v*)&s_hf[1][w][1][kt_w][ln_w][jb] = vl;
            if (s == TT) *(f32x4*)&s_h1f[n16][u0] = hf;   // final h1 for FC
        }
        __syncthreads();
    }

    // ---- epilogue: out[b0+i] = h1_last . Wfc + bfc ----
    if (tid < NBB) {
        float a = bfc[0];
        for (int j = 0; j < HH; ++j) a = fmaf(Wfc[j], s_h1f[tid][j], a);
        out[b0 + tid] = a;
    }
}

extern "C" void kernel_launch(void* const* d_in, const int* in_sizes, int n_in,
                              void* d_out, int out_size, void* d_ws, size_t ws_size,
                              hipStream_t stream) {
    const float* x    = (const float*)d_in[0];
    const float* Wih0 = (const float*)d_in[1];
    const float* Whh0 = (const float*)d_in[2];
    const float* bih0 = (const float*)d_in[3];
    const float* bhh0 = (const float*)d_in[4];
    const float* Wih1 = (const float*)d_in[5];
    const float* Whh1 = (const float*)d_in[6];
    const float* bih1 = (const float*)d_in[7];
    const float* bhh1 = (const float*)d_in[8];
    const float* Wfc  = (const float*)d_in[9];
    const float* bfc  = (const float*)d_in[10];
    float* out = (float*)d_out;

    lstm_mfma2<<<dim3(BB / NBB), dim3(256), 0, stream>>>(
        x, Wih0, Whh0, bih0, bhh0, Wih1, Whh1, bih1, bhh1, Wfc, bfc, out);
}

// Round 7
// 1037.436 us; speedup vs baseline: 1.0821x; 1.0821x over previous
//
#include <hip/hip_runtime.h>

#define BB  1024
#define TT  512
#define HH  64
#define NBB 16          // batches per block (MFMA N=16); grid = 64 blocks

typedef __attribute__((ext_vector_type(8))) short  short8;   // 8 bf16 = MFMA A/B frag
typedef __attribute__((ext_vector_type(4))) short  short4v;  // 8 B
typedef __attribute__((ext_vector_type(4))) float  f32x4;    // MFMA C/D frag

__device__ __forceinline__ unsigned short f2bf(float f) {
    unsigned u = __float_as_uint(f);
    u += 0x7FFF + ((u >> 16) & 1);          // round-to-nearest-even
    return (unsigned short)(u >> 16);
}
__device__ __forceinline__ float bf2f(unsigned short s) {
    return __uint_as_float(((unsigned)s) << 16);
}
__device__ __forceinline__ float sigm(float v) { return 1.0f / (1.0f + __expf(-v)); }
__device__ __forceinline__ float tanh_(float v) { return fmaf(2.0f, sigm(2.0f * v), -1.0f); }

// Split-bf16 MFMA fused 2-layer LSTM, v3: three wave types, each owning ONE
// 256x64 matrix (A-frags = 64 VGPRs) so every wave fits its register budget
// with slack (R2-R6 law: over-subscribed waves => silent per-step churn).
//   type0 W0: gates0(s) = Wih0*x + b0 + Whh0*h0(s-1), nonlin -> h0(s)
//   type1 P : P(s) = Wih1*h0(s-1) + b1            (linear, C-frags -> LDS)
//   type2 H1: gates1(s-2) = P(s-1) + Whh1*h1(s-3), nonlin -> h1(s-2)
// Depth-3 pipeline, parity double-buffers, ONE barrier/step.
// 12 waves (768 thr) = 3/SIMD, one of each type per SIMD (wid%4 spread).
// waves_per_eu(3,3) -> ~170-reg target; unified demand ~152.
__global__ __launch_bounds__(768)
__attribute__((amdgpu_waves_per_eu(3, 3)))
void lstm_mfma3(const float* __restrict__ x,     // [B,T] (I=1)
                const float* __restrict__ Wih0,  // [256]
                const float* __restrict__ Whh0,  // [256,64]
                const float* __restrict__ bih0,  // [256]
                const float* __restrict__ bhh0,  // [256]
                const float* __restrict__ Wih1,  // [256,64]
                const float* __restrict__ Whh1,  // [256,64]
                const float* __restrict__ bih1,  // [256]
                const float* __restrict__ bhh1,  // [256]
                const float* __restrict__ Wfc,   // [64]
                const float* __restrict__ bfc,   // [1]
                float* __restrict__ out)         // [B]
{
    __shared__ __align__(16) float          s_x[NBB][TT + 1];          // 32.8 KB
    // h fragments, B-operand order: [parity][hi/lo][kt][lane][j]  (8 KB each)
    __shared__ __align__(16) unsigned short s_h0[2][2][2][64][8];
    __shared__ __align__(16) unsigned short s_h1[2][2][2][64][8];
    // P exchange, C-frag order: [parity][G][gi][lane][r]          (32 KB)
    __shared__ __align__(16) float          s_P[2][4][4][64][4];
    __shared__ __align__(16) float          s_h1f[NBB][HH + 4];        // 4.3 KB

    const int tid  = threadIdx.x;
    const int lane = tid & 63;
    const int wid  = tid >> 6;    // 0..11
    const int type = wid % 3;     // 0=W0, 1=P, 2=H1
    const int G    = wid / 3;     // unit group 0..3 (tiles {G,G+4,G+8,G+12})
    const int q    = lane >> 4;   // quad
    const int n16  = lane & 15;   // batch column
    const int b0   = blockIdx.x * NBB;

    // ---- one-time: A fragments (hi/lo split of this type's matrix) ----
    // A-frag (16x16x32): lane holds A[m = n16][k = 8q + j], j = 0..7.
    short8 Ah[4][2], Al[4][2];
    float  scA[4][4], scB[4][4];   // W0: bias0,xw ; P: bias1,- ; H1: -,-

    const float* Wmat = (type == 0) ? Whh0 : (type == 1) ? Wih1 : Whh1;
    for (int gi = 0; gi < 4; ++gi) {
        const int rowA = 64 * gi + 16 * G + n16;
        for (int kt = 0; kt < 2; ++kt) {
            const float* src = Wmat + rowA * 64 + 32 * kt + 8 * q;
            short8 hv, lv;
            for (int j = 0; j < 8; ++j) {
                const float wv = src[j];
                const unsigned short hs = f2bf(wv);
                hv[j] = (short)hs;
                lv[j] = (short)f2bf(wv - bf2f(hs));
            }
            Ah[gi][kt] = hv; Al[gi][kt] = lv;
        }
        for (int r = 0; r < 4; ++r) {
            const int row = 64 * gi + 16 * G + 4 * q + r;   // C/D row 4q+r
            if (type == 0)      { scA[gi][r] = bih0[row] + bhh0[row]; scB[gi][r] = Wih0[row]; }
            else if (type == 1) { scA[gi][r] = bih1[row] + bhh1[row]; scB[gi][r] = 0.0f; }
            else                { scA[gi][r] = 0.0f;                  scB[gi][r] = 0.0f; }
        }
    }

    // ---- stage x (coalesced) + zero h fragment buffers ----
    for (int i = tid; i < NBB * TT; i += 768) {
        const int nb = i >> 9, pos = i & (TT - 1);
        s_x[nb][pos] = x[(b0 + nb) * TT + pos];
    }
    for (int i = tid; i < (int)(sizeof(s_h0) / 4); i += 768) {
        ((unsigned*)s_h0)[i] = 0u;
        ((unsigned*)s_h1)[i] = 0u;
    }

    float c[4] = {0, 0, 0, 0};    // W0: c0 ; H1: c1 ; P: unused

    // h-frag write address components (unit u0 = 16G + 4q)
    const int u0   = 16 * G + 4 * q;
    const int kt_w = u0 >> 5;
    const int ln_w = (((u0 >> 3) & 3) << 4) + n16;
    const int jb   = u0 & 7;

    __syncthreads();

#pragma unroll 2
    for (int s = 0; s <= TT + 1; ++s) {
        const int rp = (s + 1) & 1;   // read parity  (state written at step s-1)
        const int wp = s & 1;         // write parity (state written this step)

        if (type == 0) {
            // ---- W0: gates0(t=s), active s in [0, TT) ----
            if (s < TT) {
                short8 Bh[2], Bl[2];
#pragma unroll
                for (int kt = 0; kt < 2; ++kt) {
                    Bh[kt] = *(const short8*)&s_h0[rp][0][kt][lane][0];
                    Bl[kt] = *(const short8*)&s_h0[rp][1][kt][lane][0];
                }
                const float xv = s_x[n16][s];
                f32x4 acc[4];
#pragma unroll
                for (int gi = 0; gi < 4; ++gi) {
                    f32x4 a;
#pragma unroll
                    for (int r = 0; r < 4; ++r) a[r] = fmaf(scB[gi][r], xv, scA[gi][r]);
#pragma unroll
                    for (int kt = 0; kt < 2; ++kt) {
                        a = __builtin_amdgcn_mfma_f32_16x16x32_bf16(Ah[gi][kt], Bh[kt], a, 0, 0, 0);
                        a = __builtin_amdgcn_mfma_f32_16x16x32_bf16(Ah[gi][kt], Bl[kt], a, 0, 0, 0);
                        a = __builtin_amdgcn_mfma_f32_16x16x32_bf16(Al[gi][kt], Bh[kt], a, 0, 0, 0);
                    }
                    acc[gi] = a;
                }
                short4v vh, vl;
#pragma unroll
                for (int r = 0; r < 4; ++r) {
                    const float i_ = sigm(acc[0][r]);
                    const float f_ = sigm(acc[1][r]);
                    const float g_ = tanh_(acc[2][r]);
                    const float o_ = sigm(acc[3][r]);
                    c[r] = fmaf(f_, c[r], i_ * g_);
                    const float h = o_ * tanh_(c[r]);
                    const unsigned short hs = f2bf(h);
                    vh[r] = (short)hs;
                    vl[r] = (short)f2bf(h - bf2f(hs));
                }
                *(short4v*)&s_h0[wp][0][kt_w][ln_w][jb] = vh;
                *(short4v*)&s_h0[wp][1][kt_w][ln_w][jb] = vl;
            }
        } else if (type == 1) {
            // ---- P: P(s) = Wih1*h0(s-1) + bias1, active s in [1, TT] ----
            if (s >= 1 && s <= TT) {
                short8 Bh[2], Bl[2];
#pragma unroll
                for (int kt = 0; kt < 2; ++kt) {
                    Bh[kt] = *(const short8*)&s_h0[rp][0][kt][lane][0];
                    Bl[kt] = *(const short8*)&s_h0[rp][1][kt][lane][0];
                }
#pragma unroll
                for (int gi = 0; gi < 4; ++gi) {
                    f32x4 a;
#pragma unroll
                    for (int r = 0; r < 4; ++r) a[r] = scA[gi][r];
#pragma unroll
                    for (int kt = 0; kt < 2; ++kt) {
                        a = __builtin_amdgcn_mfma_f32_16x16x32_bf16(Ah[gi][kt], Bh[kt], a, 0, 0, 0);
                        a = __builtin_amdgcn_mfma_f32_16x16x32_bf16(Ah[gi][kt], Bl[kt], a, 0, 0, 0);
                        a = __builtin_amdgcn_mfma_f32_16x16x32_bf16(Al[gi][kt], Bh[kt], a, 0, 0, 0);
                    }
                    *(f32x4*)&s_P[wp][G][gi][lane][0] = a;
                }
            }
        } else {
            // ---- H1: gates1(t=s-2) = P(s-1) + Whh1*h1(s-3), active s in [2, TT+1] ----
            if (s >= 2) {
                short8 Bh[2], Bl[2];
#pragma unroll
                for (int kt = 0; kt < 2; ++kt) {
                    Bh[kt] = *(const short8*)&s_h1[rp][0][kt][lane][0];
                    Bl[kt] = *(const short8*)&s_h1[rp][1][kt][lane][0];
                }
                f32x4 acc[4];
#pragma unroll
                for (int gi = 0; gi < 4; ++gi) {
                    f32x4 a = *(const f32x4*)&s_P[rp][G][gi][lane][0];
#pragma unroll
                    for (int kt = 0; kt < 2; ++kt) {
                        a = __builtin_amdgcn_mfma_f32_16x16x32_bf16(Ah[gi][kt], Bh[kt], a, 0, 0, 0);
                        a = __builtin_amdgcn_mfma_f32_16x16x32_bf16(Ah[gi][kt], Bl[kt], a, 0, 0, 0);
                        a = __builtin_amdgcn_mfma_f32_16x16x32_bf16(Al[gi][kt], Bh[kt], a, 0, 0, 0);
                    }
                    acc[gi] = a;
                }
                short4v vh, vl;
                f32x4 hf;
#pragma unroll
                for (int r = 0; r < 4; ++r) {
                    const float i_ = sigm(acc[0][r]);
                    const float f_ = sigm(acc[1][r]);
                    const float g_ = tanh_(acc[2][r]);
                    const float o_ = sigm(acc[3][r]);
                    c[r] = fmaf(f_, c[r], i_ * g_);
                    const float h = o_ * tanh_(c[r]);
                    const unsigned short hs = f2bf(h);
                    vh[r] = (short)hs;
                    vl[r] = (short)f2bf(h - bf2f(hs));
                    hf[r] = h;
                }
                *(short4v*)&s_h1[wp][0][kt_w][ln_w][jb] = vh;
                *(short4v*)&s_h1[wp][1][kt_w][ln_w][jb] = vl;
                if (s == TT + 1) *(f32x4*)&s_h1f[n16][u0] = hf;   // final h1(511)
            }
        }
        __syncthreads();
    }

    // ---- epilogue: out[b0+i] = h1_last . Wfc + bfc ----
    if (tid < NBB) {
        float a = bfc[0];
        for (int j = 0; j < HH; ++j) a = fmaf(Wfc[j], s_h1f[tid][j], a);
        out[b0 + tid] = a;
    }
}

extern "C" void kernel_launch(void* const* d_in, const int* in_sizes, int n_in,
                              void* d_out, int out_size, void* d_ws, size_t ws_size,
                              hipStream_t stream) {
    const float* x    = (const float*)d_in[0];
    const float* Wih0 = (const float*)d_in[1];
    const float* Whh0 = (const float*)d_in[2];
    const float* bih0 = (const float*)d_in[3];
    const float* bhh0 = (const float*)d_in[4];
    const float* Wih1 = (const float*)d_in[5];
    const float* Whh1 = (const float*)d_in[6];
    const float* bih1 = (const float*)d_in[7];
    const float* bhh1 = (const float*)d_in[8];
    const float* Wfc  = (const float*)d_in[9];
    const float* bfc  = (const float*)d_in[10];
    float* out = (float*)d_out;

    lstm_mfma3<<<dim3(BB / NBB), dim3(768), 0, stream>>>(
        x, Wih0, Whh0, bih0, bhh0, Wih1, Whh1, bih1, bhh1, Wfc, bfc, out);
}